// Round 10
// baseline (674.364 us; speedup 1.0000x reference)
//
#include <hip/hip_runtime.h>
#include <hip/hip_bf16.h>

// ---------------------------------------------------------------------------
// BipartiteGConv, bucketed-LDS-reduce formulation:
//   prologue: WiT/WoT/WcatT bf16 tables + deg histogram
//   mfma_proj: rhs = bf16(input@Wi+bi), lhs = bf16(other@Wo)   (one launch)
//   scan1+scan2fin: rowoff = excl-scan(deg); bucketCursor[b]=rowoff[b*256]
//   partitionA: counting-sort edges into 256-row buckets (u64 {r,lj,bf16 w});
//               per-block LDS hist + one reservation per (block,bucket) ->
//               contiguous runs, cache-line-exclusive writes, NO XCD deps.
//   bucket_reduce: 1 block owns 1 bucket: S[256][64] f32 in LDS, ds_add_f32
//                  accumulation of leaky(rhs+lhs[lj]+w*We); S out bf16.
//   final_mfma: out = [S|input]@Wcat + deg*bcomb + bout  (MFMA 16 rows/wave)
//
// R9: scatter WRITE 41MB for 4MB payload -> blockIdx&7->XCD heuristic FAILED;
//     line ping-pong persists. Fix: per-block-exclusive write runs (phase A)
//     + per-bucket-exclusive block (phase B) — correct under ANY placement.
//     Also: gaps between dispatches measured small -> mid-tier kernels are
//     the cost; fuse scatter+reduce via LDS S, delete pay/pk/Xb/scan3.
// R8: 4B packed payload; R7: MFMA GEMMs; R6: occupancy; R3: no fp atomics.
// ---------------------------------------------------------------------------

#define NBUCK_CAP 512  // supports N_IN <= 131072 (actual: 100000 -> 391)

typedef short short8 __attribute__((ext_vector_type(8)));
typedef float f32x4  __attribute__((ext_vector_type(4)));

static __device__ __forceinline__ float bf2f(unsigned u) {
    return __uint_as_float(u << 16);
}
static __device__ __forceinline__ unsigned f2bf(float f) {  // RNE
    unsigned u = __float_as_uint(f);
    return (u + 0x7fffu + ((u >> 16) & 1u)) >> 16;
}

// prep weight tables + deg histogram, one launch.
__global__ void prologue(const float* __restrict__ Wi, const float* __restrict__ Wo,
                         const float* __restrict__ Wf, const float* __restrict__ bf,
                         const float* __restrict__ Wout,
                         unsigned short* __restrict__ WiT,
                         unsigned short* __restrict__ WoT,
                         unsigned short* __restrict__ WcatT,
                         float* __restrict__ bcomb,
                         const int* __restrict__ rj, int* __restrict__ deg, int E) {
    const int id = blockIdx.x * blockDim.x + threadIdx.x;
    if (id < 8192) {                       // WcatT[n][k]
        int n = id >> 7, k = id & 127;
        float v;
        if (k < 64) {
            v = 0.f;
#pragma unroll 8
            for (int j = 0; j < 64; ++j) v = fmaf(Wf[k * 64 + j], Wout[j * 64 + n], v);
        } else {
            v = Wout[k * 64 + n];
        }
        WcatT[id] = (unsigned short)f2bf(v);
    } else if (id < 8256) {                // bcomb
        int n = id - 8192;
        float v = 0.f;
#pragma unroll 8
        for (int j = 0; j < 64; ++j) v = fmaf(bf[j], Wout[j * 64 + n], v);
        bcomb[n] = v;
    } else if (id < 12352) {               // WiT[n][k] = Wi[k][n]
        int t = id - 8256, n = t >> 6, k = t & 63;
        WiT[t] = (unsigned short)f2bf(Wi[k * 64 + n]);
    } else if (id < 16448) {               // WoT
        int t = id - 12352, n = t >> 6, k = t & 63;
        WoT[t] = (unsigned short)f2bf(Wo[k * 64 + n]);
    }
    const int st = gridDim.x * blockDim.x;
    for (int i = id; i < E; i += st) atomicAdd(&deg[rj[i]], 1);
}

// Y[N,64] = bf16(X@W + b) via MFMA, 16 rows/wave. Handles both projections.
static __device__ __forceinline__ void proj_core(const float* __restrict__ X,
                                                 const unsigned short* __restrict__ WT,
                                                 const float* __restrict__ b,
                                                 unsigned short* __restrict__ Y,
                                                 int N, int bid) {
    const int lane = threadIdx.x & 63;
    const int wave = (bid * (int)blockDim.x + (int)threadIdx.x) >> 6;
    const long long base = (long long)wave * 16;
    if (base >= N) return;
    const int r15 = lane & 15, hi = lane >> 4;
    long long arow = base + r15;
    if (arow >= N) arow = N - 1;

    short8 afr[2];
#pragma unroll
    for (int s = 0; s < 2; ++s) {
        const int kb = s * 32 + hi * 8;
        const float* px = X + arow * 64 + kb;
        float4 x0 = *(const float4*)px;
        float4 x1 = *(const float4*)(px + 4);
        short8 a;
        a[0] = (short)f2bf(x0.x); a[1] = (short)f2bf(x0.y);
        a[2] = (short)f2bf(x0.z); a[3] = (short)f2bf(x0.w);
        a[4] = (short)f2bf(x1.x); a[5] = (short)f2bf(x1.y);
        a[6] = (short)f2bf(x1.z); a[7] = (short)f2bf(x1.w);
        afr[s] = a;
    }
    const f32x4 z = {0.f, 0.f, 0.f, 0.f};
    f32x4 acc[4] = {z, z, z, z};
#pragma unroll
    for (int t = 0; t < 4; ++t)
#pragma unroll
        for (int s = 0; s < 2; ++s) {
            short8 bb = *(const short8*)(WT + (t * 16 + r15) * 64 + s * 32 + hi * 8);
            acc[t] = __builtin_amdgcn_mfma_f32_16x16x32_bf16(afr[s], bb, acc[t], 0, 0, 0);
        }
#pragma unroll
    for (int t = 0; t < 4; ++t) {
        const int col = t * 16 + r15;
        const float bv = b ? b[col] : 0.f;
#pragma unroll
        for (int j = 0; j < 4; ++j) {
            long long row = base + hi * 4 + j;
            if (row < N) Y[row * 64 + col] = (unsigned short)f2bf(acc[t][j] + bv);
        }
    }
}

__global__ void mfma_proj(const float* __restrict__ input, const float* __restrict__ other,
                          const unsigned short* __restrict__ WiT,
                          const unsigned short* __restrict__ WoT,
                          const float* __restrict__ bi,
                          unsigned short* __restrict__ rhs,
                          unsigned short* __restrict__ lhs,
                          int N_IN, int N_OT, int gbA) {
    if ((int)blockIdx.x < gbA) proj_core(input, WiT, bi, rhs, N_IN, blockIdx.x);
    else                       proj_core(other, WoT, nullptr, lhs, N_OT, blockIdx.x - gbA);
}

// Exclusive scan of deg, block-local (1024/block).
__global__ void scan1_kernel(const int* __restrict__ deg, int* __restrict__ rowoff,
                             int* __restrict__ blksum, int N) {
    __shared__ int s[1024];
    const int tid = threadIdx.x;
    const int i = blockIdx.x * 1024 + tid;
    int v = (i < N) ? deg[i] : 0;
    s[tid] = v;
    __syncthreads();
    for (int off = 1; off < 1024; off <<= 1) {
        int t = (tid >= off) ? s[tid - off] : 0;
        __syncthreads();
        s[tid] += t;
        __syncthreads();
    }
    if (i < N) rowoff[i] = s[tid] - v;
    if (tid == 1023) blksum[blockIdx.x] = s[1023];
}

// Scan block sums, finalize rowoff in place, set rowoff[N]=E, init bucketCursor.
__global__ void scan2fin(int* __restrict__ blksum, int* __restrict__ rowoff,
                         int* __restrict__ bucketCursor, int nb, int nbuck,
                         int N, int E) {
    __shared__ int s[1024];
    __shared__ int ex[1024];
    const int tid = threadIdx.x;
    int v = (tid < nb) ? blksum[tid] : 0;
    s[tid] = v;
    __syncthreads();
    for (int off = 1; off < 1024; off <<= 1) {
        int t = (tid >= off) ? s[tid - off] : 0;
        __syncthreads();
        s[tid] += t;
        __syncthreads();
    }
    ex[tid] = s[tid] - v;
    __syncthreads();
    for (int i = tid; i < N; i += 1024) rowoff[i] += ex[i >> 10];
    if (tid == 0) rowoff[N] = E;
    __syncthreads();
    for (int b = tid; b < nbuck; b += 1024) bucketCursor[b] = rowoff[b << 8];
}

// Phase A: counting-sort edges into 256-row buckets. Per-block: LDS hist over
// its contiguous chunk -> one global reservation per (block,bucket) -> place.
// Per-block runs are ~chunk/nbuck entries -> cache-line-exclusive writes.
__global__ void partitionA(const int* __restrict__ rj, const int* __restrict__ lj,
                           const float* __restrict__ wts,
                           int* __restrict__ bucketCursor,
                           unsigned long long* __restrict__ bkt, int E, int nblk) {
    __shared__ int cnt[NBUCK_CAP];
    const int chunk = (E + nblk - 1) / nblk;
    const int c0 = blockIdx.x * chunk;
    const int c1 = (c0 + chunk < E) ? c0 + chunk : E;
    for (int b = threadIdx.x; b < NBUCK_CAP; b += blockDim.x) cnt[b] = 0;
    __syncthreads();
    for (int i = c0 + threadIdx.x; i < c1; i += blockDim.x)
        atomicAdd(&cnt[rj[i] >> 8], 1);
    __syncthreads();
    for (int b = threadIdx.x; b < NBUCK_CAP; b += blockDim.x) {
        int c = cnt[b];
        cnt[b] = c ? atomicAdd(&bucketCursor[b], c) : 0;  // now holds write base
    }
    __syncthreads();
    for (int i = c0 + threadIdx.x; i < c1; i += blockDim.x) {
        int r = rj[i];
        int pos = atomicAdd(&cnt[r >> 8], 1);
        unsigned pk = (unsigned)lj[i] | (f2bf(wts[i]) << 16);
        bkt[pos] = ((unsigned long long)r << 32) | pk;
    }
}

// Phase B: one block per bucket. S[256][64] f32 in LDS; waves stream the
// bucket's edges, gather lhs[lj]/rhs[r], ds_add_f32 accumulate; bf16 out.
__global__ __launch_bounds__(1024) void bucket_reduce(
        const unsigned short* __restrict__ rhs, const unsigned short* __restrict__ lhs,
        const unsigned long long* __restrict__ bkt, const float* __restrict__ We,
        const int* __restrict__ rowoff, unsigned short* __restrict__ S, int N) {
    __shared__ float Sl[256 * 64];  // 64 KB
    const int rbase = blockIdx.x << 8;
    const int rend  = (rbase + 256 < N) ? rbase + 256 : N;
    for (int i = threadIdx.x; i < 256 * 64; i += blockDim.x) Sl[i] = 0.f;
    const int lane = threadIdx.x & 63;
    const int wv   = threadIdx.x >> 6;   // 16 waves
    const float wev = We[lane];
    const int beg = rowoff[rbase], end = rowoff[rend];
    __syncthreads();
    int e = beg + wv;
    for (; e + 7 * 16 < end; e += 128) {   // 8 edges in flight per wave
        unsigned long long p[8];
#pragma unroll
        for (int j = 0; j < 8; ++j) p[j] = bkt[e + j * 16];
        float av[8], rv[8];
#pragma unroll
        for (int j = 0; j < 8; ++j) {
            av[j] = bf2f(lhs[(size_t)(p[j] & 0xffffu) * 64 + lane]);
            rv[j] = bf2f(rhs[(size_t)(p[j] >> 32) * 64 + lane]);
        }
#pragma unroll
        for (int j = 0; j < 8; ++j) {
            float m = rv[j] + av[j] + bf2f((unsigned)(p[j] >> 16) & 0xffffu) * wev;
            float val = (m >= 0.f) ? m : 0.01f * m;
            atomicAdd(&Sl[(((int)(p[j] >> 32) - rbase) << 6) + lane], val);
        }
    }
    for (; e < end; e += 16) {
        unsigned long long p = bkt[e];
        float m = bf2f(rhs[(size_t)(p >> 32) * 64 + lane])
                + bf2f(lhs[(size_t)(p & 0xffffu) * 64 + lane])
                + bf2f((unsigned)(p >> 16) & 0xffffu) * wev;
        float val = (m >= 0.f) ? m : 0.01f * m;
        atomicAdd(&Sl[(((int)(p >> 32) - rbase) << 6) + lane], val);
    }
    __syncthreads();
    const int nel = (rend - rbase) << 6;
    for (int i = threadIdx.x; i < nel; i += blockDim.x)
        S[(size_t)rbase * 64 + i] = (unsigned short)f2bf(Sl[i]);
}

// out = [S|input]@Wcat + deg*bcomb + bout, MFMA, 16 rows/wave. input f32
// converted in-register (no Xb intermediate).
__global__ void final_mfma(const unsigned short* __restrict__ S,
                           const float* __restrict__ input,
                           const unsigned short* __restrict__ WcatT,
                           const float* __restrict__ bcomb,
                           const float* __restrict__ bout,
                           const int* __restrict__ deg,
                           float* __restrict__ out, int N) {
    const int lane = threadIdx.x & 63;
    const int wave = (blockIdx.x * blockDim.x + threadIdx.x) >> 6;
    const long long base = (long long)wave * 16;
    if (base >= N) return;
    const int r15 = lane & 15, hi = lane >> 4;
    long long arow = base + r15;
    if (arow >= N) arow = N - 1;

    short8 afr[4];
#pragma unroll
    for (int s = 0; s < 2; ++s)
        afr[s] = *(const short8*)(S + arow * 64 + s * 32 + hi * 8);
#pragma unroll
    for (int s = 0; s < 2; ++s) {
        const float* px = input + arow * 64 + s * 32 + hi * 8;
        float4 x0 = *(const float4*)px;
        float4 x1 = *(const float4*)(px + 4);
        short8 a;
        a[0] = (short)f2bf(x0.x); a[1] = (short)f2bf(x0.y);
        a[2] = (short)f2bf(x0.z); a[3] = (short)f2bf(x0.w);
        a[4] = (short)f2bf(x1.x); a[5] = (short)f2bf(x1.y);
        a[6] = (short)f2bf(x1.z); a[7] = (short)f2bf(x1.w);
        afr[2 + s] = a;
    }

    const f32x4 z = {0.f, 0.f, 0.f, 0.f};
    f32x4 acc[4] = {z, z, z, z};
#pragma unroll
    for (int t = 0; t < 4; ++t)
#pragma unroll
        for (int s = 0; s < 4; ++s) {
            short8 bb = *(const short8*)(WcatT + (t * 16 + r15) * 128 + s * 32 + hi * 8);
            acc[t] = __builtin_amdgcn_mfma_f32_16x16x32_bf16(afr[s], bb, acc[t], 0, 0, 0);
        }

    float dj[4];
#pragma unroll
    for (int j = 0; j < 4; ++j) {
        long long rr = base + hi * 4 + j;
        dj[j] = (rr < N) ? (float)deg[rr] : 0.f;
    }
#pragma unroll
    for (int t = 0; t < 4; ++t) {
        const int col = t * 16 + r15;
        const float bc = bcomb[col];
        const float bo = bout[col];
#pragma unroll
        for (int j = 0; j < 4; ++j) {
            long long rr = base + hi * 4 + j;
            if (rr < N) out[rr * 64 + col] = fmaf(dj[j], bc, acc[t][j] + bo);
        }
    }
}

extern "C" void kernel_launch(void* const* d_in, const int* in_sizes, int n_in,
                              void* d_out, int out_size, void* d_ws, size_t ws_size,
                              hipStream_t stream) {
    const float* input = (const float*)d_in[0];
    const float* other = (const float*)d_in[1];
    const int*   rj    = (const int*)d_in[2];
    const int*   lj    = (const int*)d_in[3];
    const float* wts   = (const float*)d_in[4];
    const float* Wi    = (const float*)d_in[5];
    const float* bi    = (const float*)d_in[6];
    const float* Wo    = (const float*)d_in[7];
    const float* We    = (const float*)d_in[8];
    const float* Wf    = (const float*)d_in[9];
    const float* bf    = (const float*)d_in[10];
    const float* Wout  = (const float*)d_in[11];
    const float* bout  = (const float*)d_in[12];
    float* out = (float*)d_out;

    const int N_IN = in_sizes[0] / 64;
    const int N_OT = in_sizes[1] / 64;
    const int E    = in_sizes[2];
    const int nb1   = (N_IN + 1023) / 1024;
    const int nbuck = (N_IN + 255) / 256;

    char* ws = (char*)d_ws;
    unsigned long long* bkt = (unsigned long long*)ws; ws += (size_t)E * 8;
    unsigned short* WiT   = (unsigned short*)ws;  ws += 4096 * 2;
    unsigned short* WoT   = (unsigned short*)ws;  ws += 4096 * 2;
    unsigned short* WcatT = (unsigned short*)ws;  ws += 8192 * 2;
    float* bcomb = (float*)ws;                    ws += 64 * sizeof(float);
    int* deg     = (int*)ws;                      ws += (size_t)N_IN * sizeof(int);
    int* rowoff  = (int*)ws;                      ws += ((size_t)N_IN + 2) * sizeof(int);
    int* bucketCursor = (int*)ws;                 ws += NBUCK_CAP * sizeof(int);
    int* blksum  = (int*)ws;                      ws += 1024 * sizeof(int);
    unsigned short* rhs = (unsigned short*)ws;    ws += (size_t)N_IN * 64 * 2;
    unsigned short* lhs = (unsigned short*)ws;    ws += (size_t)N_OT * 64 * 2;
    unsigned short* S   = (unsigned short*)ws;    ws += (size_t)N_IN * 64 * 2;

    hipMemsetAsync(deg, 0, (size_t)N_IN * sizeof(int), stream);

    prologue<<<1024, 256, 0, stream>>>(Wi, Wo, Wf, bf, Wout, WiT, WoT, WcatT, bcomb,
                                       rj, deg, E);

    const int gbA = (N_IN + 63) / 64;
    const int gbB = (N_OT + 63) / 64;
    mfma_proj<<<gbA + gbB, 256, 0, stream>>>(input, other, WiT, WoT, bi,
                                             rhs, lhs, N_IN, N_OT, gbA);

    scan1_kernel<<<nb1, 1024, 0, stream>>>(deg, rowoff, blksum, N_IN);
    scan2fin<<<1, 1024, 0, stream>>>(blksum, rowoff, bucketCursor, nb1, nbuck, N_IN, E);

    partitionA<<<128, 256, 0, stream>>>(rj, lj, wts, bucketCursor, bkt, E, 128);

    bucket_reduce<<<nbuck, 1024, 0, stream>>>(rhs, lhs, bkt, We, rowoff, S, N_IN);

    final_mfma<<<gbA, 256, 0, stream>>>(S, input, WcatT, bcomb, bout, deg, out, N_IN);
}